// Round 5
// baseline (266.523 us; speedup 1.0000x reference)
//
#include <hip/hip_runtime.h>
#include <hip/hip_bf16.h>
#include <cstdint>

#define N_TOK 4096
#define KTOP  64
#define DIM   1024
#define NLAT  16384
#define NCHUNK 8      // 128 cols/chunk -> 2 MB fp8 per chunk, pinned per-XCD

typedef __bf16 bf16x8 __attribute__((ext_vector_type(8)));
typedef float  floatx4 __attribute__((ext_vector_type(4)));
typedef float  floatx2 __attribute__((ext_vector_type(2)));

#define GLOBAL_AS(p) ((const __attribute__((address_space(1))) void*)(p))
#define LDS_AS(p)    ((__attribute__((address_space(3))) void*)(p))

__device__ inline unsigned short f2bf(float f){
  unsigned int u = __float_as_uint(f);
  unsigned int r = (u + 0x7fffu + ((u >> 16) & 1u)) >> 16;  // RNE
  return (unsigned short)r;
}

// Fused prep: [0,1024) x->bf16 | [1024,1280) Wskip->bf16 | [1280,3328) Wdec->chunked fp8
//             [3328,3840) ystats (colsum + sum y^2), 8 rows/block
__global__ __launch_bounds__(256) void prep(
    const float* __restrict__ x, const float* __restrict__ Wsk,
    const float* __restrict__ Wd, const float* __restrict__ y,
    unsigned short* __restrict__ xb, unsigned short* __restrict__ wb,
    unsigned char* __restrict__ wdf,
    float* __restrict__ colsum, float* __restrict__ sumsq){
  const int b = blockIdx.x;
  const int t = threadIdx.x;
  if (b < 1024){
    int i0 = b * 1024 + t;
    #pragma unroll
    for (int i = 0; i < 4; i++){
      float4 v = ((const float4*)x)[i0 + i * 256];
      ushort4 o; o.x = f2bf(v.x); o.y = f2bf(v.y); o.z = f2bf(v.z); o.w = f2bf(v.w);
      ((ushort4*)xb)[i0 + i * 256] = o;
    }
  } else if (b < 1280){
    int i0 = (b - 1024) * 1024 + t;
    #pragma unroll
    for (int i = 0; i < 4; i++){
      float4 v = ((const float4*)Wsk)[i0 + i * 256];
      ushort4 o; o.x = f2bf(v.x); o.y = f2bf(v.y); o.z = f2bf(v.z); o.w = f2bf(v.w);
      ((ushort4*)wb)[i0 + i * 256] = o;
    }
  } else if (b < 3328){
    int lat0 = (b - 1280) * 8;
    const int chunk = t >> 5;          // 4 cols/thread -> chunk = (4t)/128
    const int off   = (t & 31) * 4;    // byte offset in 128B chunk row
    #pragma unroll
    for (int r = 0; r < 8; r++){
      int lat = lat0 + r;
      float4 v = ((const float4*)(Wd + (size_t)lat * DIM))[t];
      int p = __builtin_amdgcn_cvt_pk_fp8_f32(v.x, v.y, 0, false);
      p     = __builtin_amdgcn_cvt_pk_fp8_f32(v.z, v.w, p, true);
      *(int*)(wdf + ((size_t)chunk * NLAT + lat) * 128 + off) = p;
    }
  } else {
    const int r0 = (b - 3328) * 8;
    float4 cs = {0.f, 0.f, 0.f, 0.f};
    float sq = 0.f;
    #pragma unroll
    for (int r = 0; r < 8; r++){
      float4 v = ((const float4*)(y + (size_t)(r0 + r) * DIM))[t];
      cs.x += v.x; cs.y += v.y; cs.z += v.z; cs.w += v.w;
      sq += v.x*v.x + v.y*v.y + v.z*v.z + v.w*v.w;
    }
    atomicAdd(&colsum[t*4+0], cs.x);
    atomicAdd(&colsum[t*4+1], cs.y);
    atomicAdd(&colsum[t*4+2], cs.z);
    atomicAdd(&colsum[t*4+3], cs.w);
    #pragma unroll
    for (int off = 32; off > 0; off >>= 1) sq += __shfl_down(sq, off, 64);
    __shared__ float s_red[4];
    if ((t & 63) == 0) s_red[t >> 6] = sq;
    __syncthreads();
    if (t == 0) atomicAdd(sumsq, s_red[0] + s_red[1] + s_red[2] + s_red[3]);
  }
}

// 128 rows x 64 cols tile -> 512 blocks (2 blocks/CU). m97-style staging.
__global__ __launch_bounds__(256) void skip_gemm(
    const unsigned short* __restrict__ xb,
    const unsigned short* __restrict__ wb,
    const float* __restrict__ b_dec,
    float* __restrict__ out){
  __shared__ unsigned short As[128][32];
  __shared__ unsigned short Bs[64][32];
  const int row0 = blockIdx.x * 128;
  const int col0 = blockIdx.y * 64;
  const int t    = threadIdx.x;
  const int lane = t & 63;
  const int w    = t >> 6;
  const int wr   = w * 32;
  const int lm   = lane & 15;
  const int kq   = lane >> 4;
  const int sr   = t >> 2;
  const int sc   = (t & 3) * 8;

  floatx4 acc[2][4] = {};

  for (int k0 = 0; k0 < DIM; k0 += 32){
    __builtin_amdgcn_global_load_lds(GLOBAL_AS(xb + (size_t)(row0 + sr) * DIM + k0 + sc),
                                     LDS_AS(&As[sr][sc]), 16, 0, 0);
    __builtin_amdgcn_global_load_lds(GLOBAL_AS(xb + (size_t)(row0 + 64 + sr) * DIM + k0 + sc),
                                     LDS_AS(&As[64 + sr][sc]), 16, 0, 0);
    __builtin_amdgcn_global_load_lds(GLOBAL_AS(wb + (size_t)(col0 + sr) * DIM + k0 + sc),
                                     LDS_AS(&Bs[sr][sc]), 16, 0, 0);
    __syncthreads();
    bf16x8 af[2], bfr[4];
    #pragma unroll
    for (int mi = 0; mi < 2; mi++) af[mi] = *(const bf16x8*)(&As[wr + mi * 16 + lm][kq * 8]);
    #pragma unroll
    for (int ni = 0; ni < 4; ni++) bfr[ni] = *(const bf16x8*)(&Bs[ni * 16 + lm][kq * 8]);
    #pragma unroll
    for (int mi = 0; mi < 2; mi++)
      #pragma unroll
      for (int ni = 0; ni < 4; ni++)
        acc[mi][ni] = __builtin_amdgcn_mfma_f32_16x16x32_bf16(af[mi], bfr[ni], acc[mi][ni], 0, 0, 0);
    __syncthreads();
  }

  const int rq = (lane >> 4) * 4;   // C/D: col=lane&15, row=(lane>>4)*4+reg
  #pragma unroll
  for (int mi = 0; mi < 2; mi++){
    #pragma unroll
    for (int ni = 0; ni < 4; ni++){
      int col = col0 + ni * 16 + lm;
      float bd = b_dec[col];
      #pragma unroll
      for (int r = 0; r < 4; r++){
        int row = row0 + wr + mi * 16 + rq + r;
        out[(size_t)row * DIM + col] = acc[mi][ni][r] + bd;
      }
    }
  }
}

// Chunked fp8 decode, conflict-free packed LDS, unroll 16.
__global__ __launch_bounds__(256) void decode_residual(
    const float* __restrict__ y,
    const float* __restrict__ la,
    const int*   __restrict__ li,
    const unsigned char* __restrict__ Wdf,   // [NCHUNK][NLAT][128] fp8 e4m3
    const float* __restrict__ pe,
    const float* __restrict__ pes,
    float* __restrict__ out,
    float* __restrict__ sse){
  const int chunk = blockIdx.x & 7;
  const int tok0  = (blockIdx.x >> 3) * 16;
  const int t  = threadIdx.x;
  const int tl = t >> 4;       // token lane 0..15
  const int cl = t & 15;       // col lane (8 cols each)
  __shared__ uint2 s_ai[16][66];   // .x = act bits, .y = idx*128 (byte row offset); stride 66
  __shared__ float s_red[4];
  #pragma unroll
  for (int i = 0; i < 4; i++){
    int e = t + i * 256;                 // (tok = e>>6, k = e&63)
    int tok = e >> 6, k = e & 63;
    int id = li[(tok0 + tok) * KTOP + k];
    float a = (la[(tok0 + tok) * KTOP + k] + pe[id]) * pes[id];
    s_ai[tok][k] = make_uint2(__float_as_uint(a), (unsigned)id * 128u);
  }
  __syncthreads();
  const int n = tok0 + tl;
  const unsigned char* Wbase = Wdf + (size_t)chunk * NLAT * 128 + cl * 8;
  float* op = out + (size_t)n * DIM + chunk * 128 + cl * 8;
  const float* yp = y + (size_t)n * DIM + chunk * 128 + cl * 8;
  float4 o0 = ((const float4*)op)[0], o1 = ((const float4*)op)[1];
  float4 y0 = ((const float4*)yp)[0], y1 = ((const float4*)yp)[1];
  float acc[8] = {};
  #pragma unroll 16
  for (int k = 0; k < KTOP; k++){
    uint2 p = s_ai[tl][k];
    const float a = __uint_as_float(p.x);
    const uint2 wv = *(const uint2*)(Wbase + p.y);
    floatx2 c0 = __builtin_amdgcn_cvt_pk_f32_fp8(wv.x, false);
    floatx2 c1 = __builtin_amdgcn_cvt_pk_f32_fp8(wv.x, true);
    floatx2 c2 = __builtin_amdgcn_cvt_pk_f32_fp8(wv.y, false);
    floatx2 c3 = __builtin_amdgcn_cvt_pk_f32_fp8(wv.y, true);
    acc[0] += a * c0.x; acc[1] += a * c0.y;
    acc[2] += a * c1.x; acc[3] += a * c1.y;
    acc[4] += a * c2.x; acc[5] += a * c2.y;
    acc[6] += a * c3.x; acc[7] += a * c3.y;
  }
  acc[0] += o0.x; acc[1] += o0.y; acc[2] += o0.z; acc[3] += o0.w;
  acc[4] += o1.x; acc[5] += o1.y; acc[6] += o1.z; acc[7] += o1.w;
  ((float4*)op)[0] = make_float4(acc[0], acc[1], acc[2], acc[3]);
  ((float4*)op)[1] = make_float4(acc[4], acc[5], acc[6], acc[7]);
  float e0 = y0.x - acc[0], e1 = y0.y - acc[1], e2 = y0.z - acc[2], e3 = y0.w - acc[3];
  float e4 = y1.x - acc[4], e5 = y1.y - acc[5], e6 = y1.z - acc[6], e7 = y1.w - acc[7];
  float s = e0*e0 + e1*e1 + e2*e2 + e3*e3 + e4*e4 + e5*e5 + e6*e6 + e7*e7;
  #pragma unroll
  for (int off = 32; off > 0; off >>= 1) s += __shfl_down(s, off, 64);
  if ((t & 63) == 0) s_red[t >> 6] = s;
  __syncthreads();
  if (t == 0) atomicAdd(sse, s_red[0] + s_red[1] + s_red[2] + s_red[3]);
}

__global__ __launch_bounds__(256) void fvu_kernel(
    const float* __restrict__ ws, float* __restrict__ fvu_out){
  const int t = threadIdx.x;
  float4 c = ((const float4*)(ws + 4))[t];
  float s = c.x*c.x + c.y*c.y + c.z*c.z + c.w*c.w;
  #pragma unroll
  for (int off = 32; off > 0; off >>= 1) s += __shfl_down(s, off, 64);
  __shared__ float s_red[4];
  if ((t & 63) == 0) s_red[t >> 6] = s;
  __syncthreads();
  if (t == 0){
    float ss = s_red[0] + s_red[1] + s_red[2] + s_red[3];
    float tv = ws[1] - ss / (float)N_TOK;
    fvu_out[0] = ws[0] / tv;
  }
}

extern "C" void kernel_launch(void* const* d_in, const int* in_sizes, int n_in,
                              void* d_out, int out_size, void* d_ws, size_t ws_size,
                              hipStream_t stream){
  const float* x   = (const float*)d_in[0];
  const float* y   = (const float*)d_in[1];
  const float* la  = (const float*)d_in[2];
  const int*   li  = (const int*)d_in[3];
  const float* Wd  = (const float*)d_in[4];
  const float* bd  = (const float*)d_in[5];
  const float* pe  = (const float*)d_in[6];
  const float* pes = (const float*)d_in[7];
  const float* Wsk = (const float*)d_in[8];
  float* out = (float*)d_out;

  float* accs = (float*)d_ws;  // [0]=sse [1]=sumsq [4..1028)=colsum
  unsigned short* xb  = (unsigned short*)((char*)d_ws + 8192);
  unsigned short* wb  = xb + (size_t)N_TOK * DIM;
  unsigned char*  wdf = (unsigned char*)(wb + (size_t)DIM * DIM);

  hipMemsetAsync(d_ws, 0, 8192, stream);
  prep<<<3840, 256, 0, stream>>>(x, Wsk, Wd, y, xb, wb, wdf, accs + 4, accs + 1);
  skip_gemm<<<dim3(N_TOK / 128, DIM / 64), 256, 0, stream>>>(xb, wb, bd, out);
  decode_residual<<<(N_TOK / 16) * NCHUNK, 256, 0, stream>>>(y, la, li, wdf, pe, pes, out, accs);
  fvu_kernel<<<1, 256, 0, stream>>>(accs, out + (size_t)N_TOK * DIM);
}

// Round 6
// 229.551 us; speedup vs baseline: 1.1611x; 1.1611x over previous
//
#include <hip/hip_runtime.h>
#include <hip/hip_bf16.h>
#include <cstdint>

#define N_TOK 4096
#define KTOP  64
#define DIM   1024
#define NLAT  16384
#define NCHUNK 8      // 128 cols/chunk -> 2 MB fp8 per chunk, pinned per-XCD

typedef __bf16 bf16x8 __attribute__((ext_vector_type(8)));
typedef float  floatx4 __attribute__((ext_vector_type(4)));
typedef float  floatx2 __attribute__((ext_vector_type(2)));

#define GLOBAL_AS(p) ((const __attribute__((address_space(1))) void*)(p))
#define LDS_AS(p)    ((__attribute__((address_space(3))) void*)(p))

__device__ inline unsigned short f2bf(float f){
  unsigned int u = __float_as_uint(f);
  unsigned int r = (u + 0x7fffu + ((u >> 16) & 1u)) >> 16;  // RNE
  return (unsigned short)r;
}

// Fused prep, heaviest branch FIRST so it overlaps instead of tailing:
// [0,128)      ystats: colsum + sum y^2, 32 rows/block (atomics kept at 128-block contention)
// [128,2176)   Wdec -> chunked fp8 e4m3, 8 latents/block
// [2176,2432)  Wskip -> bf16 (RNE)
__global__ __launch_bounds__(256) void prep(
    const float* __restrict__ Wsk, const float* __restrict__ Wd,
    const float* __restrict__ y,
    unsigned short* __restrict__ wb, unsigned char* __restrict__ wdf,
    float* __restrict__ colsum, float* __restrict__ sumsq){
  const int b = blockIdx.x;
  const int t = threadIdx.x;
  if (b < 128){
    const int r0 = b * 32;
    float4 cs = {0.f, 0.f, 0.f, 0.f};
    float sq = 0.f;
    #pragma unroll 4
    for (int r = 0; r < 32; r++){
      float4 v = ((const float4*)(y + (size_t)(r0 + r) * DIM))[t];
      cs.x += v.x; cs.y += v.y; cs.z += v.z; cs.w += v.w;
      sq += v.x*v.x + v.y*v.y + v.z*v.z + v.w*v.w;
    }
    atomicAdd(&colsum[t*4+0], cs.x);
    atomicAdd(&colsum[t*4+1], cs.y);
    atomicAdd(&colsum[t*4+2], cs.z);
    atomicAdd(&colsum[t*4+3], cs.w);
    #pragma unroll
    for (int off = 32; off > 0; off >>= 1) sq += __shfl_down(sq, off, 64);
    __shared__ float s_red[4];
    if ((t & 63) == 0) s_red[t >> 6] = sq;
    __syncthreads();
    if (t == 0) atomicAdd(sumsq, s_red[0] + s_red[1] + s_red[2] + s_red[3]);
  } else if (b < 2176){
    int lat0 = (b - 128) * 8;
    const int chunk = t >> 5;          // 4 cols/thread -> chunk = (4t)/128
    const int off   = (t & 31) * 4;    // byte offset in 128B chunk row
    #pragma unroll
    for (int r = 0; r < 8; r++){
      int lat = lat0 + r;
      float4 v = ((const float4*)(Wd + (size_t)lat * DIM))[t];
      int p = __builtin_amdgcn_cvt_pk_fp8_f32(v.x, v.y, 0, false);
      p     = __builtin_amdgcn_cvt_pk_fp8_f32(v.z, v.w, p, true);
      *(int*)(wdf + ((size_t)chunk * NLAT + lat) * 128 + off) = p;
    }
  } else {
    int i0 = (b - 2176) * 1024 + t;
    #pragma unroll
    for (int i = 0; i < 4; i++){
      float4 v = ((const float4*)Wsk)[i0 + i * 256];
      ushort4 o; o.x = f2bf(v.x); o.y = f2bf(v.y); o.z = f2bf(v.z); o.w = f2bf(v.w);
      ((ushort4*)wb)[i0 + i * 256] = o;
    }
  }
}

// 128 rows x 64 cols tile. A staged as fp32 via global_load_lds with XOR-swizzled
// source colblocks (LDS dst must stay lane-linear); truncate-pack to bf16 via v_perm.
__global__ __launch_bounds__(256) void skip_gemm(
    const float* __restrict__ x,             // fp32 [N_TOK][DIM]
    const unsigned short* __restrict__ wb,   // bf16 [DIM][DIM]
    const float* __restrict__ b_dec,
    float* __restrict__ out){
  __shared__ float As[128][32];            // 16 KB; row r holds colblk c = g ^ (r&7)
  __shared__ unsigned short Bs[64][32];    // 4 KB, plain m97 layout
  const int row0 = blockIdx.x * 128;
  const int col0 = blockIdx.y * 64;
  const int t    = threadIdx.x;
  const int lane = t & 63;
  const int w    = t >> 6;
  const int wr   = w * 32;
  const int lm   = lane & 15;
  const int kq   = lane >> 4;
  // A staging: lane t covers LDS row (t>>3), colblk (t&7); global colblk swizzled
  const int ar = t >> 3;                 // 0..31 per call
  const int ag = (t & 7) ^ (ar & 7);     // swizzled global colblk (4 floats each)
  // B staging
  const int brow = t >> 2;
  const int bcol = (t & 3) * 8;

  floatx4 acc[2][4] = {};

  for (int k0 = 0; k0 < DIM; k0 += 32){
    #pragma unroll
    for (int i = 0; i < 4; i++){
      __builtin_amdgcn_global_load_lds(
          GLOBAL_AS(x + (size_t)(row0 + i * 32 + ar) * DIM + k0 + ag * 4),
          LDS_AS(&As[i * 32 + ar][(t & 7) * 4]), 16, 0, 0);
    }
    __builtin_amdgcn_global_load_lds(GLOBAL_AS(wb + (size_t)(col0 + brow) * DIM + k0 + bcol),
                                     LDS_AS(&Bs[brow][bcol]), 16, 0, 0);
    __syncthreads();
    bf16x8 af[2], bfr[4];
    #pragma unroll
    for (int mi = 0; mi < 2; mi++){
      const int r = wr + mi * 16 + lm;
      const int c0 = (2 * kq) ^ (r & 7);
      const int c1 = (2 * kq + 1) ^ (r & 7);
      float4 f0 = *(const float4*)(&As[r][c0 * 4]);
      float4 f1 = *(const float4*)(&As[r][c1 * 4]);
      union { bf16x8 v; unsigned int u[4]; } pk;
      pk.u[0] = __builtin_amdgcn_perm(__float_as_uint(f0.y), __float_as_uint(f0.x), 0x07060302);
      pk.u[1] = __builtin_amdgcn_perm(__float_as_uint(f0.w), __float_as_uint(f0.z), 0x07060302);
      pk.u[2] = __builtin_amdgcn_perm(__float_as_uint(f1.y), __float_as_uint(f1.x), 0x07060302);
      pk.u[3] = __builtin_amdgcn_perm(__float_as_uint(f1.w), __float_as_uint(f1.z), 0x07060302);
      af[mi] = pk.v;
    }
    #pragma unroll
    for (int ni = 0; ni < 4; ni++) bfr[ni] = *(const bf16x8*)(&Bs[ni * 16 + lm][kq * 8]);
    #pragma unroll
    for (int mi = 0; mi < 2; mi++)
      #pragma unroll
      for (int ni = 0; ni < 4; ni++)
        acc[mi][ni] = __builtin_amdgcn_mfma_f32_16x16x32_bf16(af[mi], bfr[ni], acc[mi][ni], 0, 0, 0);
    __syncthreads();
  }

  const int rq = (lane >> 4) * 4;   // C/D: col=lane&15, row=(lane>>4)*4+reg
  #pragma unroll
  for (int mi = 0; mi < 2; mi++){
    #pragma unroll
    for (int ni = 0; ni < 4; ni++){
      int col = col0 + ni * 16 + lm;
      float bd = b_dec[col];
      #pragma unroll
      for (int r = 0; r < 4; r++){
        int row = row0 + wr + mi * 16 + rq + r;
        out[(size_t)row * DIM + col] = acc[mi][ni][r] + bd;
      }
    }
  }
}

// Chunked fp8 decode, conflict-free packed LDS, unroll 16.
__global__ __launch_bounds__(256) void decode_residual(
    const float* __restrict__ y,
    const float* __restrict__ la,
    const int*   __restrict__ li,
    const unsigned char* __restrict__ Wdf,   // [NCHUNK][NLAT][128] fp8 e4m3
    const float* __restrict__ pe,
    const float* __restrict__ pes,
    float* __restrict__ out,
    float* __restrict__ sse){
  const int chunk = blockIdx.x & 7;
  const int tok0  = (blockIdx.x >> 3) * 16;
  const int t  = threadIdx.x;
  const int tl = t >> 4;       // token lane 0..15
  const int cl = t & 15;       // col lane (8 cols each)
  __shared__ uint2 s_ai[16][66];   // .x = act bits, .y = idx*128 (byte row offset)
  __shared__ float s_red[4];
  #pragma unroll
  for (int i = 0; i < 4; i++){
    int e = t + i * 256;
    int tok = e >> 6, k = e & 63;
    int id = li[(tok0 + tok) * KTOP + k];
    float a = (la[(tok0 + tok) * KTOP + k] + pe[id]) * pes[id];
    s_ai[tok][k] = make_uint2(__float_as_uint(a), (unsigned)id * 128u);
  }
  __syncthreads();
  const int n = tok0 + tl;
  const unsigned char* Wbase = Wdf + (size_t)chunk * NLAT * 128 + cl * 8;
  float* op = out + (size_t)n * DIM + chunk * 128 + cl * 8;
  const float* yp = y + (size_t)n * DIM + chunk * 128 + cl * 8;
  float4 o0 = ((const float4*)op)[0], o1 = ((const float4*)op)[1];
  float4 y0 = ((const float4*)yp)[0], y1 = ((const float4*)yp)[1];
  float acc[8] = {};
  #pragma unroll 16
  for (int k = 0; k < KTOP; k++){
    uint2 p = s_ai[tl][k];
    const float a = __uint_as_float(p.x);
    const uint2 wv = *(const uint2*)(Wbase + p.y);
    floatx2 c0 = __builtin_amdgcn_cvt_pk_f32_fp8(wv.x, false);
    floatx2 c1 = __builtin_amdgcn_cvt_pk_f32_fp8(wv.x, true);
    floatx2 c2 = __builtin_amdgcn_cvt_pk_f32_fp8(wv.y, false);
    floatx2 c3 = __builtin_amdgcn_cvt_pk_f32_fp8(wv.y, true);
    acc[0] += a * c0.x; acc[1] += a * c0.y;
    acc[2] += a * c1.x; acc[3] += a * c1.y;
    acc[4] += a * c2.x; acc[5] += a * c2.y;
    acc[6] += a * c3.x; acc[7] += a * c3.y;
  }
  acc[0] += o0.x; acc[1] += o0.y; acc[2] += o0.z; acc[3] += o0.w;
  acc[4] += o1.x; acc[5] += o1.y; acc[6] += o1.z; acc[7] += o1.w;
  ((float4*)op)[0] = make_float4(acc[0], acc[1], acc[2], acc[3]);
  ((float4*)op)[1] = make_float4(acc[4], acc[5], acc[6], acc[7]);
  float e0 = y0.x - acc[0], e1 = y0.y - acc[1], e2 = y0.z - acc[2], e3 = y0.w - acc[3];
  float e4 = y1.x - acc[4], e5 = y1.y - acc[5], e6 = y1.z - acc[6], e7 = y1.w - acc[7];
  float s = e0*e0 + e1*e1 + e2*e2 + e3*e3 + e4*e4 + e5*e5 + e6*e6 + e7*e7;
  #pragma unroll
  for (int off = 32; off > 0; off >>= 1) s += __shfl_down(s, off, 64);
  if ((t & 63) == 0) s_red[t >> 6] = s;
  __syncthreads();
  if (t == 0) atomicAdd(sse, s_red[0] + s_red[1] + s_red[2] + s_red[3]);
}

__global__ __launch_bounds__(256) void fvu_kernel(
    const float* __restrict__ ws, float* __restrict__ fvu_out){
  const int t = threadIdx.x;
  float4 c = ((const float4*)(ws + 4))[t];
  float s = c.x*c.x + c.y*c.y + c.z*c.z + c.w*c.w;
  #pragma unroll
  for (int off = 32; off > 0; off >>= 1) s += __shfl_down(s, off, 64);
  __shared__ float s_red[4];
  if ((t & 63) == 0) s_red[t >> 6] = s;
  __syncthreads();
  if (t == 0){
    float ss = s_red[0] + s_red[1] + s_red[2] + s_red[3];
    float tv = ws[1] - ss / (float)N_TOK;
    fvu_out[0] = ws[0] / tv;
  }
}

extern "C" void kernel_launch(void* const* d_in, const int* in_sizes, int n_in,
                              void* d_out, int out_size, void* d_ws, size_t ws_size,
                              hipStream_t stream){
  const float* x   = (const float*)d_in[0];
  const float* y   = (const float*)d_in[1];
  const float* la  = (const float*)d_in[2];
  const int*   li  = (const int*)d_in[3];
  const float* Wd  = (const float*)d_in[4];
  const float* bd  = (const float*)d_in[5];
  const float* pe  = (const float*)d_in[6];
  const float* pes = (const float*)d_in[7];
  const float* Wsk = (const float*)d_in[8];
  float* out = (float*)d_out;

  float* accs = (float*)d_ws;  // [0]=sse [1]=sumsq [4..1028)=colsum
  unsigned short* wb  = (unsigned short*)((char*)d_ws + 8192);
  unsigned char*  wdf = (unsigned char*)(wb + (size_t)DIM * DIM);

  hipMemsetAsync(d_ws, 0, 8192, stream);
  prep<<<2432, 256, 0, stream>>>(Wsk, Wd, y, wb, wdf, accs + 4, accs + 1);
  skip_gemm<<<dim3(N_TOK / 128, DIM / 64), 256, 0, stream>>>(x, wb, bd, out);
  decode_residual<<<(N_TOK / 16) * NCHUNK, 256, 0, stream>>>(y, la, li, wdf, pe, pes, out, accs);
  fvu_kernel<<<1, 256, 0, stream>>>(accs, out + (size_t)N_TOK * DIM);
}